// Round 9
// baseline (716.156 us; speedup 1.0000x reference)
//
#include <hip/hip_runtime.h>
#include <stdint.h>

#define LSEQ 1024
#define HDIM 1024
#define DDIM 2048
#define BL 2048
#define NST 16
#define LC 256          // chunk length in tokens
#define XROWS (LC + 3)  // chunk rows + 3-row conv halo

typedef unsigned short u16;
typedef __attribute__((ext_vector_type(8))) short bf16x8;
typedef __attribute__((ext_vector_type(4))) float f32x4;

static __device__ __forceinline__ float silu_f(float v) { return v / (1.f + __expf(-v)); }
static __device__ __forceinline__ u16 f2bf(float f) {
  union { float f; unsigned int i; } c; c.f = f;
  unsigned int r = c.i + 0x7fffu + ((c.i >> 16) & 1u);
  return (u16)(r >> 16);
}

// ---------------- cast fp32 -> bf16 (weights, once per launch) ----------------
__global__ __launch_bounds__(256) void k_castw(const float* __restrict__ src,
                                               u16* __restrict__ dst) {
  int idx = blockIdx.x * 256 + threadIdx.x;
  float4 v = ((const float4*)src)[idx];
  ushort4 o;
  o.x = f2bf(v.x); o.y = f2bf(v.y); o.z = f2bf(v.z); o.w = f2bf(v.w);
  ((ushort4*)dst)[idx] = o;
}

// ---------------- rmsnorm + cast: xnb[row] = bf16(inp*scale*norm_w) ----------------
__global__ __launch_bounds__(256) void k_normcast(const float* __restrict__ inp,
                                                  const float* __restrict__ nw,
                                                  u16* __restrict__ xnb) {
  int row = blockIdx.x;
  int t = threadIdx.x;
  float4 xv = *(const float4*)(inp + (size_t)row * HDIM + t * 4);
  float ss = xv.x * xv.x + xv.y * xv.y + xv.z * xv.z + xv.w * xv.w;
  for (int off = 32; off > 0; off >>= 1) ss += __shfl_down(ss, off);
  __shared__ float red[4];
  if ((t & 63) == 0) red[t >> 6] = ss;
  __syncthreads();
  float tot = red[0] + red[1] + red[2] + red[3];
  float scale = rsqrtf(tot * (1.f / HDIM) + 1e-6f);
  float4 nv = *(const float4*)(nw + t * 4);
  ushort4 o;
  o.x = f2bf(xv.x * scale * nv.x); o.y = f2bf(xv.y * scale * nv.y);
  o.z = f2bf(xv.z * scale * nv.z); o.w = f2bf(xv.w * scale * nv.w);
  *(ushort4*)(xnb + (size_t)row * HDIM + t * 4) = o;
}

// ---------------- halo: copy last 3 x-rows of previous chunk to rows [0,3) ----------------
__global__ __launch_bounds__(256) void k_halo(float* __restrict__ xgb) {
  int idx = blockIdx.x * 256 + threadIdx.x;  // 2 batches * 3 rows * 2048 cols = 12288
  int b = idx / (3 * DDIM);
  int rem = idx - b * 3 * DDIM;
  int r = rem / DDIM;
  int c = rem - r * DDIM;
  xgb[(size_t)(b * XROWS + r) * 4096 + c] = xgb[(size_t)(b * XROWS + LC + r) * 4096 + c];
}

// ---------------- K1: in_proj MFMA GEMM: xg = xnb . w1b^T + b1 (fp32 out) ----------------
__global__ __launch_bounds__(256) void k_gemm1_mfma(const u16* __restrict__ A,   // [2048][1024] bf16
                                                    const u16* __restrict__ W,   // [4096][1024] bf16
                                                    const float* __restrict__ bias,
                                                    float* __restrict__ xgb, int l0) {
  __shared__ u16 Asm[64 * 40];
  __shared__ u16 Wsm[64 * 40];
  int t = threadIdx.x;
  int m0 = blockIdx.y * 64, n0 = blockIdx.x * 64;
  int srow = t >> 2, koff = (t & 3) * 8;
  int r = m0 + srow;
  int gin = ((r >> 8) << 10) + l0 + (r & 255);      // chunk row -> global BL row
  const u16* Ag = A + (size_t)gin * HDIM + koff;
  const u16* Wg = W + (size_t)(n0 + srow) * HDIM + koff;
  int w = t >> 6, lane = t & 63;
  int quad = lane >> 4, mr = lane & 15;
  f32x4 z = {0.f, 0.f, 0.f, 0.f};
  f32x4 acc0 = z, acc1 = z, acc2 = z, acc3 = z;
  const u16* arp = &Asm[(16 * w + mr) * 40 + quad * 8];
  const u16* brp = &Wsm[mr * 40 + quad * 8];
  for (int k0 = 0; k0 < HDIM; k0 += 32) {
    uint4 av = *(const uint4*)(Ag + k0);
    uint4 wv = *(const uint4*)(Wg + k0);
    __syncthreads();
    *(uint4*)(&Asm[srow * 40 + koff]) = av;
    *(uint4*)(&Wsm[srow * 40 + koff]) = wv;
    __syncthreads();
    bf16x8 af = *(const bf16x8*)arp;
    bf16x8 b0 = *(const bf16x8*)(brp);
    bf16x8 b1 = *(const bf16x8*)(brp + 16 * 40);
    bf16x8 b2 = *(const bf16x8*)(brp + 32 * 40);
    bf16x8 b3 = *(const bf16x8*)(brp + 48 * 40);
    acc0 = __builtin_amdgcn_mfma_f32_16x16x32_bf16(af, b0, acc0, 0, 0, 0);
    acc1 = __builtin_amdgcn_mfma_f32_16x16x32_bf16(af, b1, acc1, 0, 0, 0);
    acc2 = __builtin_amdgcn_mfma_f32_16x16x32_bf16(af, b2, acc2, 0, 0, 0);
    acc3 = __builtin_amdgcn_mfma_f32_16x16x32_bf16(af, b3, acc3, 0, 0, 0);
  }
  f32x4 accs[4] = {acc0, acc1, acc2, acc3};
#pragma unroll
  for (int i = 0; i < 4; i++) {
    int col = n0 + 16 * i + mr;
    float bv = bias[col];
#pragma unroll
    for (int rr2 = 0; rr2 < 4; rr2++) {
      int rr = m0 + 16 * w + quad * 4 + rr2;
      int lout = (rr >> 8) * XROWS + 3 + (rr & 255);
      xgb[(size_t)lout * 4096 + col] = accs[i][rr2] + bv;
    }
  }
}

// ---------------- K4: out_proj MFMA GEMM + bias + residual (fp32 out) ----------------
__global__ __launch_bounds__(256) void k_gemm2_mfma(const u16* __restrict__ A,   // yb [512][2048] bf16
                                                    const u16* __restrict__ W,   // wob [1024][2048] bf16
                                                    const float* __restrict__ bias,
                                                    const float* __restrict__ resid,
                                                    float* __restrict__ out, int l0) {
  __shared__ u16 Asm[64 * 40];
  __shared__ u16 Wsm[64 * 40];
  int t = threadIdx.x;
  int m0 = blockIdx.y * 64, n0 = blockIdx.x * 64;
  int srow = t >> 2, koff = (t & 3) * 8;
  const u16* Ag = A + (size_t)(m0 + srow) * DDIM + koff;
  const u16* Wg = W + (size_t)(n0 + srow) * DDIM + koff;
  int w = t >> 6, lane = t & 63;
  int quad = lane >> 4, mr = lane & 15;
  f32x4 z = {0.f, 0.f, 0.f, 0.f};
  f32x4 acc0 = z, acc1 = z, acc2 = z, acc3 = z;
  const u16* arp = &Asm[(16 * w + mr) * 40 + quad * 8];
  const u16* brp = &Wsm[mr * 40 + quad * 8];
  for (int k0 = 0; k0 < DDIM; k0 += 32) {
    uint4 av = *(const uint4*)(Ag + k0);
    uint4 wv = *(const uint4*)(Wg + k0);
    __syncthreads();
    *(uint4*)(&Asm[srow * 40 + koff]) = av;
    *(uint4*)(&Wsm[srow * 40 + koff]) = wv;
    __syncthreads();
    bf16x8 af = *(const bf16x8*)arp;
    bf16x8 b0 = *(const bf16x8*)(brp);
    bf16x8 b1 = *(const bf16x8*)(brp + 16 * 40);
    bf16x8 b2 = *(const bf16x8*)(brp + 32 * 40);
    bf16x8 b3 = *(const bf16x8*)(brp + 48 * 40);
    acc0 = __builtin_amdgcn_mfma_f32_16x16x32_bf16(af, b0, acc0, 0, 0, 0);
    acc1 = __builtin_amdgcn_mfma_f32_16x16x32_bf16(af, b1, acc1, 0, 0, 0);
    acc2 = __builtin_amdgcn_mfma_f32_16x16x32_bf16(af, b2, acc2, 0, 0, 0);
    acc3 = __builtin_amdgcn_mfma_f32_16x16x32_bf16(af, b3, acc3, 0, 0, 0);
  }
  f32x4 accs[4] = {acc0, acc1, acc2, acc3};
#pragma unroll
  for (int i = 0; i < 4; i++) {
    int col = n0 + 16 * i + mr;
    float bv = bias[col];
#pragma unroll
    for (int rr2 = 0; rr2 < 4; rr2++) {
      int rr = m0 + 16 * w + quad * 4 + rr2;
      int gout = ((rr >> 8) << 10) + l0 + (rr & 255);
      out[(size_t)gout * HDIM + col] =
          accs[i][rr2] + bv + resid[(size_t)gout * HDIM + col];
    }
  }
}

// ---------------- K2: conv+silu (in LDS) then x_proj; writes TRANSPOSED projT[96][BL] ----------------
__global__ __launch_bounds__(256) void k_xprojc(const float* __restrict__ xgb,
                                                const float* __restrict__ cw,
                                                const float* __restrict__ cb,
                                                const float* __restrict__ w,
                                                const float* __restrict__ b,
                                                float* __restrict__ projT, int l0) {
  __shared__ float row[DDIM];
  int bb = blockIdx.x >> 8, lc = blockIdx.x & 255;
  int gl = l0 + lc;
  int t = threadIdx.x;
  int d = t * 8;
  float acc[8];
#pragma unroll
  for (int i = 0; i < 8; i++) acc[i] = cb[d + i];
  float cwv[8][4];
#pragma unroll
  for (int i = 0; i < 8; i++) {
    float4 v = *(const float4*)(cw + (d + i) * 4);
    cwv[i][0] = v.x; cwv[i][1] = v.y; cwv[i][2] = v.z; cwv[i][3] = v.w;
  }
#pragma unroll
  for (int j = 0; j < 4; j++) {
    if (gl - 3 + j >= 0) {  // causal guard; halo rows valid when this holds
      const float* xr = xgb + (size_t)(bb * XROWS + lc + j) * 4096 + d;
      float4 v0 = *(const float4*)xr;
      float4 v1 = *(const float4*)(xr + 4);
      acc[0] += v0.x * cwv[0][j]; acc[1] += v0.y * cwv[1][j];
      acc[2] += v0.z * cwv[2][j]; acc[3] += v0.w * cwv[3][j];
      acc[4] += v1.x * cwv[4][j]; acc[5] += v1.y * cwv[5][j];
      acc[6] += v1.z * cwv[6][j]; acc[7] += v1.w * cwv[7][j];
    }
  }
#pragma unroll
  for (int i = 0; i < 8; i++) row[d + i] = silu_f(acc[i]);
  __syncthreads();
  int wv = t >> 6, lane = t & 63;
  const float4* row4 = (const float4*)row;
  int colT = (bb << 10) + gl;             // token column in projT
  for (int o = wv; o < 96; o += 4) {
    const float4* wr4 = (const float4*)(w + (size_t)o * DDIM);
    float s0 = 0.f, s1 = 0.f, s2 = 0.f, s3 = 0.f;
#pragma unroll
    for (int k4 = 0; k4 < 8; k4++) {
      int idx = (k4 << 6) + lane;
      float4 wv4 = wr4[idx];
      float4 rv4 = row4[idx];
      s0 += rv4.x * wv4.x; s1 += rv4.y * wv4.y;
      s2 += rv4.z * wv4.z; s3 += rv4.w * wv4.w;
    }
    float s = (s0 + s1) + (s2 + s3);
    s += __shfl_xor(s, 32); s += __shfl_xor(s, 16);
    s += __shfl_xor(s, 8);  s += __shfl_xor(s, 4);
    s += __shfl_xor(s, 2);  s += __shfl_xor(s, 1);
    if (lane == 0) projT[(size_t)o * BL + colT] = s + b[o];
  }
}

// ---------------- K3: parallel selective scan; projT[96][BL] coalesced reads ----------------
__global__ __launch_bounds__(256) void k_scan(const float* __restrict__ projT,
                                              const float* __restrict__ xgb,
                                              const float* __restrict__ cw,
                                              const float* __restrict__ cb,
                                              const float* __restrict__ dtw,
                                              const float* __restrict__ dtb,
                                              const float* __restrict__ alog,
                                              const float* __restrict__ dparam,
                                              const float* __restrict__ cs,
                                              float* __restrict__ cumA,   // [4096] carried D
                                              float* __restrict__ SA,     // [65536] carried S per n
                                              u16* __restrict__ yb, int l0) {
  __shared__ float xs[XROWS];
  __shared__ float xcs[LC];
  __shared__ float ds_s[LC];
  __shared__ float Dl[LC];
  __shared__ float dtw_s[64];
  __shared__ float wtot[4];
  __shared__ float ys[4][LC];

  int t = threadIdx.x;
  // XCD-aware swizzle: XCD x owns a contiguous 512-wide d range
  int cidx = ((blockIdx.x & 7) << 9) | (blockIdx.x >> 3);   // (b,d)
  int b = cidx >> 11;
  int d = cidx & (DDIM - 1);
  int wv = t >> 6, lane = t & 63;
  int colT = (b << 10) + l0;          // base token column in projT for this chunk

  // stage x column (with halo)
  xs[t] = (l0 == 0 && t < 3) ? 0.f : xgb[(size_t)(b * XROWS + t) * 4096 + d];
  if (t < 3) xs[LC + t] = xgb[(size_t)(b * XROWS + LC + t) * 4096 + d];
  if (t < 64) dtw_s[t] = dtw[(size_t)d * 64 + t];

  // per-thread B/C fragment preload: coalesced rows of projT
  float Bn[4][4], Cn[4][4];
#pragma unroll
  for (int r = 0; r < 4; r++) {
    int n = wv * 4 + r;
#pragma unroll
    for (int s = 0; s < 4; s++) {
      int l = (s << 6) + lane;
      Bn[r][s] = projT[(size_t)(64 + n) * BL + colT + l];
      Cn[r][s] = projT[(size_t)(80 + n) * BL + colT + l];
    }
  }
  float An[4], AnDc[4], state[4], Soff[4];
  float Dc = (l0 == 0) ? 0.f : cumA[cidx];
#pragma unroll
  for (int r = 0; r < 4; r++) {
    int n = wv * 4 + r;
    An[r] = -__expf(alog[d * NST + n]);
    AnDc[r] = An[r] * Dc;
    state[r] = cs[(size_t)(b * DDIM + d) * NST + n];
    Soff[r] = (l0 == 0) ? 0.f : SA[(cidx << 4) | n];
  }
  __syncthreads();

  // conv + silu (thread t -> token t)
  {
    float4 cwv = *(const float4*)(cw + d * 4);
    float v = cb[d] + cwv.w * xs[t + 3] + cwv.z * xs[t + 2] + cwv.y * xs[t + 1] + cwv.x * xs[t];
    xcs[t] = silu_f(v);
  }
  // delta (thread t -> token t): 64-dot over projT rows (coalesced) + softplus
  float dval;
  {
    float acc = dtb[d];
#pragma unroll
    for (int k = 0; k < 64; k++) {
      acc += projT[(size_t)k * BL + colT + t] * dtw_s[k];
    }
    dval = (acc > 20.f) ? acc : log1pf(__expf(acc));
    ds_s[t] = dval;
  }
  // prefix sum of delta: wave shfl scan + cross-wave offsets
  {
    float val = dval;
#pragma unroll
    for (int off = 1; off < 64; off <<= 1) {
      float u = __shfl_up(val, off);
      if (lane >= off) val += u;
    }
    if (lane == 63) wtot[wv] = val;
    __syncthreads();
    float woff = 0.f;
#pragma unroll
    for (int i = 0; i < 3; i++) if (i < wv) woff += wtot[i];
    Dl[t] = val + woff;
    __syncthreads();
  }

  // main scan: s outer (sequential carry), r inner (independent n)
#pragma unroll
  for (int s = 0; s < 4; s++) {
    int l = (s << 6) + lane;
    float dsl = ds_s[l];
    float De = (l == 0) ? 0.f : Dl[l - 1];
    float Di = Dl[l];
    float xcl = xcs[l];
    float yl = 0.f;
#pragma unroll
    for (int r = 0; r < 4; r++) {
      float Pprev = __expf(AnDc[r] + An[r] * De);
      float P = __expf(AnDc[r] + An[r] * Di);
      float w = (dsl * Bn[r][s] * xcl) / fmaxf(Pprev, 1e-10f);
#pragma unroll
      for (int off = 1; off < 64; off <<= 1) {
        float u = __shfl_up(w, off);
        if (lane >= off) w += u;
      }
      float S = Soff[r] + w;
      float h = S * Pprev + state[r] * P;
      yl += h * Cn[r][s];
      Soff[r] = __shfl(S, 63);
    }
    ys[wv][l] = yl;
  }
  if (lane == 0) {
#pragma unroll
    for (int r = 0; r < 4; r++) SA[(cidx << 4) | (wv * 4 + r)] = Soff[r];
  }
  if (t == 0) cumA[cidx] = Dc + Dl[LC - 1];
  __syncthreads();

  // final: y = sum over waves + D-term, gate, write (bf16 for gemm2's A operand)
  {
    float y = ys[0][t] + ys[1][t] + ys[2][t] + ys[3][t] + xcs[t] * dparam[d];
    float g = xgb[(size_t)(b * XROWS + 3 + t) * 4096 + DDIM + d];
    yb[(size_t)((b << 8) + t) * DDIM + d] = f2bf(y * silu_f(g));
  }
}

extern "C" void kernel_launch(void* const* d_in, const int* in_sizes, int n_in,
                              void* d_out, int out_size, void* d_ws, size_t ws_size,
                              hipStream_t stream) {
  const float* inp    = (const float*)d_in[0];
  const float* cstate = (const float*)d_in[1];
  const float* norm_w = (const float*)d_in[2];
  const float* w1     = (const float*)d_in[3];
  const float* b1     = (const float*)d_in[4];
  const float* convw  = (const float*)d_in[5];
  const float* convb  = (const float*)d_in[6];
  const float* xpw    = (const float*)d_in[7];
  const float* xpb    = (const float*)d_in[8];
  const float* dtw    = (const float*)d_in[9];
  const float* dtb    = (const float*)d_in[10];
  const float* alog   = (const float*)d_in[11];
  const float* dparam = (const float*)d_in[12];
  const float* wo     = (const float*)d_in[13];
  const float* bo     = (const float*)d_in[14];
  float* out = (float*)d_out;

  // workspace layout, 28,426,240 B total
  char* wsb = (char*)d_ws;
  u16*   w1b   = (u16*)(wsb + 0);            //  8,388,608 B  [4096][1024] bf16
  u16*   wob   = (u16*)(wsb + 8388608);      //  4,194,304 B  [1024][2048] bf16
  u16*   xnb   = (u16*)(wsb + 12582912);     //  4,194,304 B  [2048][1024] bf16
  float* projT = (float*)(wsb + 16777216);   //    786,432 B  [96][2048] (transposed)
  float* cumA  = (float*)(wsb + 17563648);   //     16,384 B  [4096]
  float* SA    = (float*)(wsb + 17580032);   //    262,144 B  [65536]
  float* xgb   = (float*)(wsb + 17842176);   //  8,486,912 B  [2][259][4096] f32
  u16*   yb    = (u16*)(wsb + 26329088);     //  2,097,152 B  [2][256][2048] bf16

  k_castw<<<4096, 256, 0, stream>>>(w1, w1b);
  k_castw<<<2048, 256, 0, stream>>>(wo, wob);
  k_normcast<<<BL, 256, 0, stream>>>(inp, norm_w, xnb);
  for (int c = 0; c < 4; c++) {
    int l0 = c * LC;
    if (c > 0) k_halo<<<48, 256, 0, stream>>>(xgb);
    k_gemm1_mfma<<<dim3(64, 8), 256, 0, stream>>>(xnb, w1b, b1, xgb, l0);
    k_xprojc<<<2 * LC, 256, 0, stream>>>(xgb, convw, convb, xpw, xpb, projT, l0);
    k_scan<<<2 * DDIM, 256, 0, stream>>>(projT, xgb, convw, convb, dtw, dtb,
                                         alog, dparam, cstate, cumA, SA, yb, l0);
    k_gemm2_mfma<<<dim3(16, 8), 256, 0, stream>>>(yb, wob, bo, inp, out, l0);
  }
}

// Round 10
// 636.690 us; speedup vs baseline: 1.1248x; 1.1248x over previous
//
#include <hip/hip_runtime.h>
#include <stdint.h>

#define LSEQ 1024
#define HDIM 1024
#define DDIM 2048
#define BL 2048
#define NST 16
#define LC 256          // chunk length in tokens
#define XROWS (LC + 3)  // chunk rows + 3-row conv halo

typedef unsigned short u16;
typedef __attribute__((ext_vector_type(8))) short bf16x8;
typedef __attribute__((ext_vector_type(4))) float f32x4;

static __device__ __forceinline__ float silu_f(float v) { return v / (1.f + __expf(-v)); }
static __device__ __forceinline__ u16 f2bf(float f) {
  union { float f; unsigned int i; } c; c.f = f;
  unsigned int r = c.i + 0x7fffu + ((c.i >> 16) & 1u);
  return (u16)(r >> 16);
}

// ---------------- cast fp32 -> bf16 (weights, once per launch) ----------------
__global__ __launch_bounds__(256) void k_castw(const float* __restrict__ src,
                                               u16* __restrict__ dst) {
  int idx = blockIdx.x * 256 + threadIdx.x;
  float4 v = ((const float4*)src)[idx];
  ushort4 o;
  o.x = f2bf(v.x); o.y = f2bf(v.y); o.z = f2bf(v.z); o.w = f2bf(v.w);
  ((ushort4*)dst)[idx] = o;
}

// ---------------- rmsnorm + cast: xnb[row] = bf16(inp*scale*norm_w) ----------------
__global__ __launch_bounds__(256) void k_normcast(const float* __restrict__ inp,
                                                  const float* __restrict__ nw,
                                                  u16* __restrict__ xnb) {
  int row = blockIdx.x;
  int t = threadIdx.x;
  float4 xv = *(const float4*)(inp + (size_t)row * HDIM + t * 4);
  float ss = xv.x * xv.x + xv.y * xv.y + xv.z * xv.z + xv.w * xv.w;
  for (int off = 32; off > 0; off >>= 1) ss += __shfl_down(ss, off);
  __shared__ float red[4];
  if ((t & 63) == 0) red[t >> 6] = ss;
  __syncthreads();
  float tot = red[0] + red[1] + red[2] + red[3];
  float scale = rsqrtf(tot * (1.f / HDIM) + 1e-6f);
  float4 nv = *(const float4*)(nw + t * 4);
  ushort4 o;
  o.x = f2bf(xv.x * scale * nv.x); o.y = f2bf(xv.y * scale * nv.y);
  o.z = f2bf(xv.z * scale * nv.z); o.w = f2bf(xv.w * scale * nv.w);
  *(ushort4*)(xnb + (size_t)row * HDIM + t * 4) = o;
}

// ---------------- halo: copy last 3 x-rows of previous chunk to rows [0,3) ----------------
__global__ __launch_bounds__(256) void k_halo(float* __restrict__ xgb) {
  int idx = blockIdx.x * 256 + threadIdx.x;  // 2 batches * 3 rows * 2048 cols = 12288
  int b = idx / (3 * DDIM);
  int rem = idx - b * 3 * DDIM;
  int r = rem / DDIM;
  int c = rem - r * DDIM;
  xgb[(size_t)(b * XROWS + r) * 4096 + c] = xgb[(size_t)(b * XROWS + LC + r) * 4096 + c];
}

// ---------------- K1: in_proj MFMA GEMM: xg = xnb . w1b^T + b1 (fp32 out) ----------------
__global__ __launch_bounds__(256) void k_gemm1_mfma(const u16* __restrict__ A,   // [2048][1024] bf16
                                                    const u16* __restrict__ W,   // [4096][1024] bf16
                                                    const float* __restrict__ bias,
                                                    float* __restrict__ xgb, int l0) {
  __shared__ u16 Asm[64 * 40];
  __shared__ u16 Wsm[64 * 40];
  int t = threadIdx.x;
  int m0 = blockIdx.y * 64, n0 = blockIdx.x * 64;
  int srow = t >> 2, koff = (t & 3) * 8;
  int r = m0 + srow;
  int gin = ((r >> 8) << 10) + l0 + (r & 255);      // chunk row -> global BL row
  const u16* Ag = A + (size_t)gin * HDIM + koff;
  const u16* Wg = W + (size_t)(n0 + srow) * HDIM + koff;
  int w = t >> 6, lane = t & 63;
  int quad = lane >> 4, mr = lane & 15;
  f32x4 z = {0.f, 0.f, 0.f, 0.f};
  f32x4 acc0 = z, acc1 = z, acc2 = z, acc3 = z;
  const u16* arp = &Asm[(16 * w + mr) * 40 + quad * 8];
  const u16* brp = &Wsm[mr * 40 + quad * 8];
  for (int k0 = 0; k0 < HDIM; k0 += 32) {
    uint4 av = *(const uint4*)(Ag + k0);
    uint4 wv = *(const uint4*)(Wg + k0);
    __syncthreads();
    *(uint4*)(&Asm[srow * 40 + koff]) = av;
    *(uint4*)(&Wsm[srow * 40 + koff]) = wv;
    __syncthreads();
    bf16x8 af = *(const bf16x8*)arp;
    bf16x8 b0 = *(const bf16x8*)(brp);
    bf16x8 b1 = *(const bf16x8*)(brp + 16 * 40);
    bf16x8 b2 = *(const bf16x8*)(brp + 32 * 40);
    bf16x8 b3 = *(const bf16x8*)(brp + 48 * 40);
    acc0 = __builtin_amdgcn_mfma_f32_16x16x32_bf16(af, b0, acc0, 0, 0, 0);
    acc1 = __builtin_amdgcn_mfma_f32_16x16x32_bf16(af, b1, acc1, 0, 0, 0);
    acc2 = __builtin_amdgcn_mfma_f32_16x16x32_bf16(af, b2, acc2, 0, 0, 0);
    acc3 = __builtin_amdgcn_mfma_f32_16x16x32_bf16(af, b3, acc3, 0, 0, 0);
  }
  f32x4 accs[4] = {acc0, acc1, acc2, acc3};
#pragma unroll
  for (int i = 0; i < 4; i++) {
    int col = n0 + 16 * i + mr;
    float bv = bias[col];
#pragma unroll
    for (int rr2 = 0; rr2 < 4; rr2++) {
      int rr = m0 + 16 * w + quad * 4 + rr2;
      int lout = (rr >> 8) * XROWS + 3 + (rr & 255);
      xgb[(size_t)lout * 4096 + col] = accs[i][rr2] + bv;
    }
  }
}

// ---------------- K4: out_proj MFMA GEMM + bias + residual (fp32 out) ----------------
__global__ __launch_bounds__(256) void k_gemm2_mfma(const u16* __restrict__ A,   // yb [512][2048] bf16
                                                    const u16* __restrict__ W,   // wob [1024][2048] bf16
                                                    const float* __restrict__ bias,
                                                    const float* __restrict__ resid,
                                                    float* __restrict__ out, int l0) {
  __shared__ u16 Asm[64 * 40];
  __shared__ u16 Wsm[64 * 40];
  int t = threadIdx.x;
  int m0 = blockIdx.y * 64, n0 = blockIdx.x * 64;
  int srow = t >> 2, koff = (t & 3) * 8;
  const u16* Ag = A + (size_t)(m0 + srow) * DDIM + koff;
  const u16* Wg = W + (size_t)(n0 + srow) * DDIM + koff;
  int w = t >> 6, lane = t & 63;
  int quad = lane >> 4, mr = lane & 15;
  f32x4 z = {0.f, 0.f, 0.f, 0.f};
  f32x4 acc0 = z, acc1 = z, acc2 = z, acc3 = z;
  const u16* arp = &Asm[(16 * w + mr) * 40 + quad * 8];
  const u16* brp = &Wsm[mr * 40 + quad * 8];
  for (int k0 = 0; k0 < DDIM; k0 += 32) {
    uint4 av = *(const uint4*)(Ag + k0);
    uint4 wv = *(const uint4*)(Wg + k0);
    __syncthreads();
    *(uint4*)(&Asm[srow * 40 + koff]) = av;
    *(uint4*)(&Wsm[srow * 40 + koff]) = wv;
    __syncthreads();
    bf16x8 af = *(const bf16x8*)arp;
    bf16x8 b0 = *(const bf16x8*)(brp);
    bf16x8 b1 = *(const bf16x8*)(brp + 16 * 40);
    bf16x8 b2 = *(const bf16x8*)(brp + 32 * 40);
    bf16x8 b3 = *(const bf16x8*)(brp + 48 * 40);
    acc0 = __builtin_amdgcn_mfma_f32_16x16x32_bf16(af, b0, acc0, 0, 0, 0);
    acc1 = __builtin_amdgcn_mfma_f32_16x16x32_bf16(af, b1, acc1, 0, 0, 0);
    acc2 = __builtin_amdgcn_mfma_f32_16x16x32_bf16(af, b2, acc2, 0, 0, 0);
    acc3 = __builtin_amdgcn_mfma_f32_16x16x32_bf16(af, b3, acc3, 0, 0, 0);
  }
  f32x4 accs[4] = {acc0, acc1, acc2, acc3};
#pragma unroll
  for (int i = 0; i < 4; i++) {
    int col = n0 + 16 * i + mr;
    float bv = bias[col];
#pragma unroll
    for (int rr2 = 0; rr2 < 4; rr2++) {
      int rr = m0 + 16 * w + quad * 4 + rr2;
      int gout = ((rr >> 8) << 10) + l0 + (rr & 255);
      out[(size_t)gout * HDIM + col] =
          accs[i][rr2] + bv + resid[(size_t)gout * HDIM + col];
    }
  }
}

// ---------------- K2: conv+silu (in LDS) then x_proj; token-major proj[BL][96] ----------------
__global__ __launch_bounds__(256) void k_xprojc(const float* __restrict__ xgb,
                                                const float* __restrict__ cw,
                                                const float* __restrict__ cb,
                                                const float* __restrict__ w,
                                                const float* __restrict__ b,
                                                float* __restrict__ proj, int l0) {
  __shared__ float row[DDIM];
  int bb = blockIdx.x >> 8, lc = blockIdx.x & 255;
  int gl = l0 + lc;
  int t = threadIdx.x;
  int d = t * 8;
  float acc[8];
#pragma unroll
  for (int i = 0; i < 8; i++) acc[i] = cb[d + i];
  float cwv[8][4];
#pragma unroll
  for (int i = 0; i < 8; i++) {
    float4 v = *(const float4*)(cw + (d + i) * 4);
    cwv[i][0] = v.x; cwv[i][1] = v.y; cwv[i][2] = v.z; cwv[i][3] = v.w;
  }
#pragma unroll
  for (int j = 0; j < 4; j++) {
    if (gl - 3 + j >= 0) {  // causal guard; halo rows valid when this holds
      const float* xr = xgb + (size_t)(bb * XROWS + lc + j) * 4096 + d;
      float4 v0 = *(const float4*)xr;
      float4 v1 = *(const float4*)(xr + 4);
      acc[0] += v0.x * cwv[0][j]; acc[1] += v0.y * cwv[1][j];
      acc[2] += v0.z * cwv[2][j]; acc[3] += v0.w * cwv[3][j];
      acc[4] += v1.x * cwv[4][j]; acc[5] += v1.y * cwv[5][j];
      acc[6] += v1.z * cwv[6][j]; acc[7] += v1.w * cwv[7][j];
    }
  }
#pragma unroll
  for (int i = 0; i < 8; i++) row[d + i] = silu_f(acc[i]);
  __syncthreads();
  int wv = t >> 6, lane = t & 63;
  const float4* row4 = (const float4*)row;
  int colT = (bb << 10) + gl;             // global token index
  for (int o = wv; o < 96; o += 4) {
    const float4* wr4 = (const float4*)(w + (size_t)o * DDIM);
    float s0 = 0.f, s1 = 0.f, s2 = 0.f, s3 = 0.f;
#pragma unroll
    for (int k4 = 0; k4 < 8; k4++) {
      int idx = (k4 << 6) + lane;
      float4 wv4 = wr4[idx];
      float4 rv4 = row4[idx];
      s0 += rv4.x * wv4.x; s1 += rv4.y * wv4.y;
      s2 += rv4.z * wv4.z; s3 += rv4.w * wv4.w;
    }
    float s = (s0 + s1) + (s2 + s3);
    s += __shfl_xor(s, 32); s += __shfl_xor(s, 16);
    s += __shfl_xor(s, 8);  s += __shfl_xor(s, 4);
    s += __shfl_xor(s, 2);  s += __shfl_xor(s, 1);
    if (lane == 0) proj[(size_t)colT * 96 + o] = s + b[o];
  }
}

// ---------------- K2b: transpose proj[tokens][96] -> projT[96][BL] for this chunk ----------------
__global__ __launch_bounds__(256) void k_transpose(const float* __restrict__ proj,
                                                   float* __restrict__ projT, int l0) {
  __shared__ float tile[64][97];        // +1 pad: conflict-free column reads
  int blk = blockIdx.x;                 // 8 blocks: b = blk>>2, 64-token segment = blk&3
  int b = blk >> 2;
  int tok0 = (b << 10) + l0 + (blk & 3) * 64;
  int t = threadIdx.x;
  const float* src = proj + (size_t)tok0 * 96;
#pragma unroll
  for (int i = 0; i < 24; i++) {
    int idx = t + i * 256;              // 0..6143, coalesced
    int row = idx / 96, col = idx - row * 96;
    tile[row][col] = src[idx];
  }
  __syncthreads();
  int wv = t >> 6, lane = t & 63;
#pragma unroll
  for (int i = 0; i < 24; i++) {
    int o = wv + i * 4;                 // 0..95
    projT[(size_t)o * BL + tok0 + lane] = tile[lane][o];  // full-line coalesced
  }
}

// ---------------- K3: parallel selective scan; projT[96][BL] coalesced reads ----------------
__global__ __launch_bounds__(256) void k_scan(const float* __restrict__ projT,
                                              const float* __restrict__ xgb,
                                              const float* __restrict__ cw,
                                              const float* __restrict__ cb,
                                              const float* __restrict__ dtw,
                                              const float* __restrict__ dtb,
                                              const float* __restrict__ alog,
                                              const float* __restrict__ dparam,
                                              const float* __restrict__ cs,
                                              float* __restrict__ cumA,   // [4096] carried D
                                              float* __restrict__ SA,     // [65536] carried S per n
                                              u16* __restrict__ yb, int l0) {
  __shared__ float xs[XROWS];
  __shared__ float xcs[LC];
  __shared__ float ds_s[LC];
  __shared__ float Dl[LC];
  __shared__ float dtw_s[64];
  __shared__ float wtot[4];
  __shared__ float ys[4][LC];

  int t = threadIdx.x;
  // XCD-aware swizzle: XCD x owns a contiguous 512-wide d range
  int cidx = ((blockIdx.x & 7) << 9) | (blockIdx.x >> 3);   // (b,d)
  int b = cidx >> 11;
  int d = cidx & (DDIM - 1);
  int wv = t >> 6, lane = t & 63;
  int colT = (b << 10) + l0;          // base token column in projT for this chunk

  // stage x column (with halo)
  xs[t] = (l0 == 0 && t < 3) ? 0.f : xgb[(size_t)(b * XROWS + t) * 4096 + d];
  if (t < 3) xs[LC + t] = xgb[(size_t)(b * XROWS + LC + t) * 4096 + d];
  if (t < 64) dtw_s[t] = dtw[(size_t)d * 64 + t];

  // per-thread B/C fragment preload: coalesced rows of projT
  float Bn[4][4], Cn[4][4];
#pragma unroll
  for (int r = 0; r < 4; r++) {
    int n = wv * 4 + r;
#pragma unroll
    for (int s = 0; s < 4; s++) {
      int l = (s << 6) + lane;
      Bn[r][s] = projT[(size_t)(64 + n) * BL + colT + l];
      Cn[r][s] = projT[(size_t)(80 + n) * BL + colT + l];
    }
  }
  float An[4], AnDc[4], state[4], Soff[4];
  float Dc = (l0 == 0) ? 0.f : cumA[cidx];
#pragma unroll
  for (int r = 0; r < 4; r++) {
    int n = wv * 4 + r;
    An[r] = -__expf(alog[d * NST + n]);
    AnDc[r] = An[r] * Dc;
    state[r] = cs[(size_t)(b * DDIM + d) * NST + n];
    Soff[r] = (l0 == 0) ? 0.f : SA[(cidx << 4) | n];
  }
  __syncthreads();

  // conv + silu (thread t -> token t)
  {
    float4 cwv = *(const float4*)(cw + d * 4);
    float v = cb[d] + cwv.w * xs[t + 3] + cwv.z * xs[t + 2] + cwv.y * xs[t + 1] + cwv.x * xs[t];
    xcs[t] = silu_f(v);
  }
  // delta (thread t -> token t): 64-dot over projT rows (coalesced) + softplus
  float dval;
  {
    float acc = dtb[d];
#pragma unroll
    for (int k = 0; k < 64; k++) {
      acc += projT[(size_t)k * BL + colT + t] * dtw_s[k];
    }
    dval = (acc > 20.f) ? acc : log1pf(__expf(acc));
    ds_s[t] = dval;
  }
  // prefix sum of delta: wave shfl scan + cross-wave offsets
  {
    float val = dval;
#pragma unroll
    for (int off = 1; off < 64; off <<= 1) {
      float u = __shfl_up(val, off);
      if (lane >= off) val += u;
    }
    if (lane == 63) wtot[wv] = val;
    __syncthreads();
    float woff = 0.f;
#pragma unroll
    for (int i = 0; i < 3; i++) if (i < wv) woff += wtot[i];
    Dl[t] = val + woff;
    __syncthreads();
  }

  // main scan: s outer (sequential carry), r inner (independent n)
#pragma unroll
  for (int s = 0; s < 4; s++) {
    int l = (s << 6) + lane;
    float dsl = ds_s[l];
    float De = (l == 0) ? 0.f : Dl[l - 1];
    float Di = Dl[l];
    float xcl = xcs[l];
    float yl = 0.f;
#pragma unroll
    for (int r = 0; r < 4; r++) {
      float Pprev = __expf(AnDc[r] + An[r] * De);
      float P = __expf(AnDc[r] + An[r] * Di);
      float w = (dsl * Bn[r][s] * xcl) / fmaxf(Pprev, 1e-10f);
#pragma unroll
      for (int off = 1; off < 64; off <<= 1) {
        float u = __shfl_up(w, off);
        if (lane >= off) w += u;
      }
      float S = Soff[r] + w;
      float h = S * Pprev + state[r] * P;
      yl += h * Cn[r][s];
      Soff[r] = __shfl(S, 63);
    }
    ys[wv][l] = yl;
  }
  if (lane == 0) {
#pragma unroll
    for (int r = 0; r < 4; r++) SA[(cidx << 4) | (wv * 4 + r)] = Soff[r];
  }
  if (t == 0) cumA[cidx] = Dc + Dl[LC - 1];
  __syncthreads();

  // final: y = sum over waves + D-term, gate, write (bf16 for gemm2's A operand)
  {
    float y = ys[0][t] + ys[1][t] + ys[2][t] + ys[3][t] + xcs[t] * dparam[d];
    float g = xgb[(size_t)(b * XROWS + 3 + t) * 4096 + DDIM + d];
    yb[(size_t)((b << 8) + t) * DDIM + d] = f2bf(y * silu_f(g));
  }
}

extern "C" void kernel_launch(void* const* d_in, const int* in_sizes, int n_in,
                              void* d_out, int out_size, void* d_ws, size_t ws_size,
                              hipStream_t stream) {
  const float* inp    = (const float*)d_in[0];
  const float* cstate = (const float*)d_in[1];
  const float* norm_w = (const float*)d_in[2];
  const float* w1     = (const float*)d_in[3];
  const float* b1     = (const float*)d_in[4];
  const float* convw  = (const float*)d_in[5];
  const float* convb  = (const float*)d_in[6];
  const float* xpw    = (const float*)d_in[7];
  const float* xpb    = (const float*)d_in[8];
  const float* dtw    = (const float*)d_in[9];
  const float* dtb    = (const float*)d_in[10];
  const float* alog   = (const float*)d_in[11];
  const float* dparam = (const float*)d_in[12];
  const float* wo     = (const float*)d_in[13];
  const float* bo     = (const float*)d_in[14];
  float* out = (float*)d_out;

  // workspace layout, 29,212,672 B total
  char* wsb = (char*)d_ws;
  u16*   w1b   = (u16*)(wsb + 0);            //  8,388,608 B  [4096][1024] bf16
  u16*   wob   = (u16*)(wsb + 8388608);      //  4,194,304 B  [1024][2048] bf16
  u16*   xnb   = (u16*)(wsb + 12582912);     //  4,194,304 B  [2048][1024] bf16
  float* proj  = (float*)(wsb + 16777216);   //    786,432 B  [2048][96] token-major
  float* projT = (float*)(wsb + 17563648);   //    786,432 B  [96][2048] transposed
  float* cumA  = (float*)(wsb + 18350080);   //     16,384 B  [4096]
  float* SA    = (float*)(wsb + 18366464);   //    262,144 B  [65536]
  float* xgb   = (float*)(wsb + 18628608);   //  8,486,912 B  [2][259][4096] f32
  u16*   yb    = (u16*)(wsb + 27115520);     //  2,097,152 B  [2][256][2048] bf16

  k_castw<<<4096, 256, 0, stream>>>(w1, w1b);
  k_castw<<<2048, 256, 0, stream>>>(wo, wob);
  k_normcast<<<BL, 256, 0, stream>>>(inp, norm_w, xnb);
  for (int c = 0; c < 4; c++) {
    int l0 = c * LC;
    if (c > 0) k_halo<<<48, 256, 0, stream>>>(xgb);
    k_gemm1_mfma<<<dim3(64, 8), 256, 0, stream>>>(xnb, w1b, b1, xgb, l0);
    k_xprojc<<<2 * LC, 256, 0, stream>>>(xgb, convw, convb, xpw, xpb, proj, l0);
    k_transpose<<<8, 256, 0, stream>>>(proj, projT, l0);
    k_scan<<<2 * DDIM, 256, 0, stream>>>(projT, xgb, convw, convb, dtw, dtb,
                                         alog, dparam, cstate, cumA, SA, yb, l0);
    k_gemm2_mfma<<<dim3(16, 8), 256, 0, stream>>>(yb, wob, bo, inp, out, l0);
  }
}

// Round 11
// 452.356 us; speedup vs baseline: 1.5832x; 1.4075x over previous
//
#include <hip/hip_runtime.h>
#include <stdint.h>

#define LSEQ 1024
#define HDIM 1024
#define DDIM 2048
#define BL 2048
#define NST 16
#define XR 1027          // 3 halo rows (unused, zero-pad region) + 1024 tokens

typedef unsigned short u16;
typedef __attribute__((ext_vector_type(8))) short bf16x8;
typedef __attribute__((ext_vector_type(4))) float f32x4;

static __device__ __forceinline__ float silu_f(float v) { return v / (1.f + __expf(-v)); }
static __device__ __forceinline__ float bf2f(u16 u) {
  union { float f; unsigned int i; } c; c.i = ((unsigned int)u) << 16; return c.f;
}
static __device__ __forceinline__ u16 f2bf(float f) {
  union { float f; unsigned int i; } c; c.f = f;
  unsigned int r = c.i + 0x7fffu + ((c.i >> 16) & 1u);
  return (u16)(r >> 16);
}

// ---------------- cast fp32 -> bf16 (weights, once per launch) ----------------
__global__ __launch_bounds__(256) void k_castw(const float* __restrict__ src,
                                               u16* __restrict__ dst) {
  int idx = blockIdx.x * 256 + threadIdx.x;
  float4 v = ((const float4*)src)[idx];
  ushort4 o;
  o.x = f2bf(v.x); o.y = f2bf(v.y); o.z = f2bf(v.z); o.w = f2bf(v.w);
  ((ushort4*)dst)[idx] = o;
}

// ---------------- per-row rmsnorm scale ----------------
__global__ __launch_bounds__(256) void k_rowscale(const float* __restrict__ inp,
                                                  float* __restrict__ rs) {
  int row = blockIdx.x;
  int t = threadIdx.x;
  float4 xv = *(const float4*)(inp + (size_t)row * HDIM + t * 4);
  float ss = xv.x * xv.x + xv.y * xv.y + xv.z * xv.z + xv.w * xv.w;
  for (int off = 32; off > 0; off >>= 1) ss += __shfl_down(ss, off);
  __shared__ float red[4];
  if ((t & 63) == 0) red[t >> 6] = ss;
  __syncthreads();
  if (t == 0) {
    float tot = red[0] + red[1] + red[2] + red[3];
    rs[row] = rsqrtf(tot * (1.f / HDIM) + 1e-6f);
  }
}

// ---------------- K1: in_proj MFMA GEMM, rmsnorm fused into A staging ----------------
// Full M=2048, N=4096, K=1024. 64x64 tile. Output bf16 xgb [2][XR][4096].
__global__ __launch_bounds__(256) void k_gemm1_mfma(const float* __restrict__ inp,
                                                    const u16* __restrict__ W,
                                                    const float* __restrict__ bias,
                                                    const float* __restrict__ rscale,
                                                    const float* __restrict__ nw,
                                                    u16* __restrict__ xgb) {
  __shared__ u16 Asm[64 * 40];
  __shared__ u16 Wsm[64 * 40];
  int t = threadIdx.x;
  int m0 = blockIdx.y * 64, n0 = blockIdx.x * 64;
  int srow = t >> 2, koff = (t & 3) * 8;
  int gin = m0 + srow;
  const float* Ag = inp + (size_t)gin * HDIM + koff;
  const u16* Wg = W + (size_t)(n0 + srow) * HDIM + koff;
  float scale = rscale[gin];
  int w = t >> 6, lane = t & 63;
  int quad = lane >> 4, mr = lane & 15;
  f32x4 z = {0.f, 0.f, 0.f, 0.f};
  f32x4 acc0 = z, acc1 = z, acc2 = z, acc3 = z;
  const u16* arp = &Asm[(16 * w + mr) * 40 + quad * 8];
  const u16* brp = &Wsm[mr * 40 + quad * 8];
  for (int k0 = 0; k0 < HDIM; k0 += 32) {
    float4 a0 = *(const float4*)(Ag + k0);
    float4 a1 = *(const float4*)(Ag + k0 + 4);
    float4 n0v = *(const float4*)(nw + k0 + koff);
    float4 n1v = *(const float4*)(nw + k0 + koff + 4);
    uint4 wv = *(const uint4*)(Wg + k0);
    ushort4 p0, p1;
    p0.x = f2bf(a0.x * scale * n0v.x); p0.y = f2bf(a0.y * scale * n0v.y);
    p0.z = f2bf(a0.z * scale * n0v.z); p0.w = f2bf(a0.w * scale * n0v.w);
    p1.x = f2bf(a1.x * scale * n1v.x); p1.y = f2bf(a1.y * scale * n1v.y);
    p1.z = f2bf(a1.z * scale * n1v.z); p1.w = f2bf(a1.w * scale * n1v.w);
    __syncthreads();
    *(ushort4*)(&Asm[srow * 40 + koff]) = p0;
    *(ushort4*)(&Asm[srow * 40 + koff + 4]) = p1;
    *(uint4*)(&Wsm[srow * 40 + koff]) = wv;
    __syncthreads();
    bf16x8 af = *(const bf16x8*)arp;
    bf16x8 b0 = *(const bf16x8*)(brp);
    bf16x8 b1 = *(const bf16x8*)(brp + 16 * 40);
    bf16x8 b2 = *(const bf16x8*)(brp + 32 * 40);
    bf16x8 b3 = *(const bf16x8*)(brp + 48 * 40);
    acc0 = __builtin_amdgcn_mfma_f32_16x16x32_bf16(af, b0, acc0, 0, 0, 0);
    acc1 = __builtin_amdgcn_mfma_f32_16x16x32_bf16(af, b1, acc1, 0, 0, 0);
    acc2 = __builtin_amdgcn_mfma_f32_16x16x32_bf16(af, b2, acc2, 0, 0, 0);
    acc3 = __builtin_amdgcn_mfma_f32_16x16x32_bf16(af, b3, acc3, 0, 0, 0);
  }
  f32x4 accs[4] = {acc0, acc1, acc2, acc3};
#pragma unroll
  for (int i = 0; i < 4; i++) {
    int col = n0 + 16 * i + mr;
    float bv = bias[col];
#pragma unroll
    for (int rr2 = 0; rr2 < 4; rr2++) {
      int rr = m0 + 16 * w + quad * 4 + rr2;
      int row = (rr >> 10) * XR + 3 + (rr & 1023);
      xgb[(size_t)row * 4096 + col] = f2bf(accs[i][rr2] + bv);
    }
  }
}

// ---------------- K4: out_proj MFMA GEMM + bias + residual (fp32 out) ----------------
__global__ __launch_bounds__(256) void k_gemm2_mfma(const u16* __restrict__ A,   // yb [2048][2048] bf16
                                                    const u16* __restrict__ W,   // wob [1024][2048] bf16
                                                    const float* __restrict__ bias,
                                                    const float* __restrict__ resid,
                                                    float* __restrict__ out) {
  __shared__ u16 Asm[64 * 40];
  __shared__ u16 Wsm[64 * 40];
  int t = threadIdx.x;
  int m0 = blockIdx.y * 64, n0 = blockIdx.x * 64;
  int srow = t >> 2, koff = (t & 3) * 8;
  const u16* Ag = A + (size_t)(m0 + srow) * DDIM + koff;
  const u16* Wg = W + (size_t)(n0 + srow) * DDIM + koff;
  int w = t >> 6, lane = t & 63;
  int quad = lane >> 4, mr = lane & 15;
  f32x4 z = {0.f, 0.f, 0.f, 0.f};
  f32x4 acc0 = z, acc1 = z, acc2 = z, acc3 = z;
  const u16* arp = &Asm[(16 * w + mr) * 40 + quad * 8];
  const u16* brp = &Wsm[mr * 40 + quad * 8];
  for (int k0 = 0; k0 < DDIM; k0 += 32) {
    uint4 av = *(const uint4*)(Ag + k0);
    uint4 wv = *(const uint4*)(Wg + k0);
    __syncthreads();
    *(uint4*)(&Asm[srow * 40 + koff]) = av;
    *(uint4*)(&Wsm[srow * 40 + koff]) = wv;
    __syncthreads();
    bf16x8 af = *(const bf16x8*)arp;
    bf16x8 b0 = *(const bf16x8*)(brp);
    bf16x8 b1 = *(const bf16x8*)(brp + 16 * 40);
    bf16x8 b2 = *(const bf16x8*)(brp + 32 * 40);
    bf16x8 b3 = *(const bf16x8*)(brp + 48 * 40);
    acc0 = __builtin_amdgcn_mfma_f32_16x16x32_bf16(af, b0, acc0, 0, 0, 0);
    acc1 = __builtin_amdgcn_mfma_f32_16x16x32_bf16(af, b1, acc1, 0, 0, 0);
    acc2 = __builtin_amdgcn_mfma_f32_16x16x32_bf16(af, b2, acc2, 0, 0, 0);
    acc3 = __builtin_amdgcn_mfma_f32_16x16x32_bf16(af, b3, acc3, 0, 0, 0);
  }
  f32x4 accs[4] = {acc0, acc1, acc2, acc3};
#pragma unroll
  for (int i = 0; i < 4; i++) {
    int col = n0 + 16 * i + mr;
    float bv = bias[col];
#pragma unroll
    for (int rr2 = 0; rr2 < 4; rr2++) {
      int gout = m0 + 16 * w + quad * 4 + rr2;
      out[(size_t)gout * HDIM + col] =
          accs[i][rr2] + bv + resid[(size_t)gout * HDIM + col];
    }
  }
}

// ---------------- K2: conv+silu (LDS) then x_proj; token-major proj[BL][96] ----------------
__global__ __launch_bounds__(256) void k_xprojc(const u16* __restrict__ xgb,
                                                const float* __restrict__ cw,
                                                const float* __restrict__ cb,
                                                const float* __restrict__ w,
                                                const float* __restrict__ b,
                                                float* __restrict__ proj) {
  __shared__ float row[DDIM];
  int bb = blockIdx.x >> 10, l = blockIdx.x & 1023;
  int t = threadIdx.x;
  int d = t * 8;
  float acc[8];
#pragma unroll
  for (int i = 0; i < 8; i++) acc[i] = cb[d + i];
  float cwv[8][4];
#pragma unroll
  for (int i = 0; i < 8; i++) {
    float4 v = *(const float4*)(cw + (d + i) * 4);
    cwv[i][0] = v.x; cwv[i][1] = v.y; cwv[i][2] = v.z; cwv[i][3] = v.w;
  }
#pragma unroll
  for (int j = 0; j < 4; j++) {
    if (l - 3 + j >= 0) {
      const u16* xr = xgb + (size_t)(bb * XR + l + j) * 4096 + d;
      ushort4 v0 = *(const ushort4*)xr;
      ushort4 v1 = *(const ushort4*)(xr + 4);
      acc[0] += bf2f(v0.x) * cwv[0][j]; acc[1] += bf2f(v0.y) * cwv[1][j];
      acc[2] += bf2f(v0.z) * cwv[2][j]; acc[3] += bf2f(v0.w) * cwv[3][j];
      acc[4] += bf2f(v1.x) * cwv[4][j]; acc[5] += bf2f(v1.y) * cwv[5][j];
      acc[6] += bf2f(v1.z) * cwv[6][j]; acc[7] += bf2f(v1.w) * cwv[7][j];
    }
  }
#pragma unroll
  for (int i = 0; i < 8; i++) row[d + i] = silu_f(acc[i]);
  __syncthreads();
  int wv = t >> 6, lane = t & 63;
  const float4* row4 = (const float4*)row;
  int tk = (bb << 10) + l;
  for (int o = wv; o < 96; o += 4) {
    const float4* wr4 = (const float4*)(w + (size_t)o * DDIM);
    float s0 = 0.f, s1 = 0.f, s2 = 0.f, s3 = 0.f;
#pragma unroll
    for (int k4 = 0; k4 < 8; k4++) {
      int idx = (k4 << 6) + lane;
      float4 wv4 = wr4[idx];
      float4 rv4 = row4[idx];
      s0 += rv4.x * wv4.x; s1 += rv4.y * wv4.y;
      s2 += rv4.z * wv4.z; s3 += rv4.w * wv4.w;
    }
    float s = (s0 + s1) + (s2 + s3);
    s += __shfl_xor(s, 32); s += __shfl_xor(s, 16);
    s += __shfl_xor(s, 8);  s += __shfl_xor(s, 4);
    s += __shfl_xor(s, 2);  s += __shfl_xor(s, 1);
    if (lane == 0) proj[(size_t)tk * 96 + o] = s + b[o];
  }
}

// ---------------- K2b: transpose proj[BL][96] -> projT[96][BL] ----------------
__global__ __launch_bounds__(256) void k_transpose(const float* __restrict__ proj,
                                                   float* __restrict__ projT) {
  __shared__ float tile[64][97];
  int blk = blockIdx.x;                 // 32 blocks: b = blk>>4, 64-token segment = blk&15
  int b = blk >> 4;
  int tok0 = (b << 10) + (blk & 15) * 64;
  int t = threadIdx.x;
  const float* src = proj + (size_t)tok0 * 96;
#pragma unroll
  for (int i = 0; i < 24; i++) {
    int idx = t + i * 256;
    int row = idx / 96, col = idx - row * 96;
    tile[row][col] = src[idx];
  }
  __syncthreads();
  int wv = t >> 6, lane = t & 63;
#pragma unroll
  for (int i = 0; i < 24; i++) {
    int o = wv + i * 4;
    projT[(size_t)o * BL + tok0 + lane] = tile[lane][o];
  }
}

// ---------------- K3: full-sequence selective scan, in-register segment carries ----------------
__global__ __launch_bounds__(256) void k_scan(const float* __restrict__ projT,
                                              const u16* __restrict__ xgb,
                                              const float* __restrict__ cw,
                                              const float* __restrict__ cb,
                                              const float* __restrict__ dtw,
                                              const float* __restrict__ dtb,
                                              const float* __restrict__ alog,
                                              const float* __restrict__ dparam,
                                              const float* __restrict__ cs,
                                              u16* __restrict__ yb) {
  __shared__ float xs[259];
  __shared__ float xcs[256];
  __shared__ float ds_s[256];
  __shared__ float Dl[256];
  __shared__ float dtw_s[64];
  __shared__ float wtot[4];
  __shared__ float ys[4][256];

  int t = threadIdx.x;
  // XCD-aware swizzle: XCD x owns a contiguous 512-wide d range
  int cidx = ((blockIdx.x & 7) << 9) | (blockIdx.x >> 3);   // (b,d)
  int b = cidx >> 11;
  int d = cidx & (DDIM - 1);
  int wv = t >> 6, lane = t & 63;

  if (t < 64) dtw_s[t] = dtw[(size_t)d * 64 + t];
  float4 cwv = *(const float4*)(cw + d * 4);
  float cbv = cb[d];
  float dtbv = dtb[d];
  float Dp = dparam[d];
  float An[4], state[4], Soff[4], Pcar[4];
#pragma unroll
  for (int r = 0; r < 4; r++) {
    int n = wv * 4 + r;
    An[r] = -__expf(alog[d * NST + n]);
    state[r] = cs[(size_t)(b * DDIM + d) * NST + n];
    Soff[r] = 0.f;
  }
  float Dc = 0.f;
  const u16* xcol = xgb + (size_t)(b * XR + 3) * 4096 + d;      // x half, token-row base
  const u16* gcol = xcol + DDIM;                                // gate half
  u16* ycol = yb + (size_t)(b << 10) * DDIM + d;

  for (int seg = 0; seg < 4; seg++) {
    int base = seg << 8;
    int colT = (b << 10) + base;
    // stage x tokens [base-3, base+255]
    {
      int tok = base - 3 + t;
      xs[t] = (tok < 0) ? 0.f : bf2f(xcol[(size_t)tok * 4096]);
      if (t < 3) xs[256 + t] = bf2f(xcol[(size_t)(base + 253 + t) * 4096]);
    }
    // B/C register preload for this segment (coalesced projT rows)
    float Bn[4][4], Cn[4][4];
#pragma unroll
    for (int r = 0; r < 4; r++) {
      int n = wv * 4 + r;
#pragma unroll
      for (int s = 0; s < 4; s++) {
        int l = (s << 6) + lane;
        Bn[r][s] = projT[(size_t)(64 + n) * BL + colT + l];
        Cn[r][s] = projT[(size_t)(80 + n) * BL + colT + l];
      }
    }
    __syncthreads();
    // conv + silu
    xcs[t] = silu_f(cbv + cwv.w * xs[t + 3] + cwv.z * xs[t + 2] + cwv.y * xs[t + 1] + cwv.x * xs[t]);
    // delta: 64-dot over projT rows + softplus
    float dval;
    {
      float acc = dtbv;
#pragma unroll
      for (int k = 0; k < 64; k++) acc += projT[(size_t)k * BL + colT + t] * dtw_s[k];
      dval = (acc > 20.f) ? acc : log1pf(__expf(acc));
      ds_s[t] = dval;
    }
    // prefix sum of delta (wave scan + cross-wave offsets)
    {
      float val = dval;
#pragma unroll
      for (int off = 1; off < 64; off <<= 1) {
        float u = __shfl_up(val, off);
        if (lane >= off) val += u;
      }
      if (lane == 63) wtot[wv] = val;
      __syncthreads();
      float woff = 0.f;
#pragma unroll
      for (int i = 0; i < 3; i++) if (i < wv) woff += wtot[i];
      Dl[t] = val + woff;
      __syncthreads();
    }
    float DlLast = Dl[255];
    float AnDc[4];
#pragma unroll
    for (int r = 0; r < 4; r++) { AnDc[r] = An[r] * Dc; Pcar[r] = __expf(AnDc[r]); }

    // main scan: s outer (sequential carry), r inner
#pragma unroll
    for (int s = 0; s < 4; s++) {
      int l = (s << 6) + lane;
      float dsl = ds_s[l];
      float Di = Dl[l];
      float xcl = xcs[l];
      float yl = 0.f;
#pragma unroll
      for (int r = 0; r < 4; r++) {
        float P = __expf(AnDc[r] + An[r] * Di);
        float Pp = __shfl_up(P, 1);
        if (lane == 0) Pp = Pcar[r];
        float w = (dsl * Bn[r][s] * xcl) / fmaxf(Pp, 1e-10f);
#pragma unroll
        for (int off = 1; off < 64; off <<= 1) {
          float u = __shfl_up(w, off);
          if (lane >= off) w += u;
        }
        float S = Soff[r] + w;
        float h = S * Pp + state[r] * P;
        yl += h * Cn[r][s];
        Soff[r] = __shfl(S, 63);
        Pcar[r] = __shfl(P, 63);
      }
      ys[wv][l] = yl;
    }
    __syncthreads();
    // y = wave-sum + D-term, gate, write bf16
    {
      float y = ys[0][t] + ys[1][t] + ys[2][t] + ys[3][t] + xcs[t] * Dp;
      float g = bf2f(gcol[(size_t)(base + t) * 4096]);
      ycol[(size_t)(base + t) * DDIM] = f2bf(y * silu_f(g));
    }
    Dc += DlLast;
    __syncthreads();
  }
}

extern "C" void kernel_launch(void* const* d_in, const int* in_sizes, int n_in,
                              void* d_out, int out_size, void* d_ws, size_t ws_size,
                              hipStream_t stream) {
  const float* inp    = (const float*)d_in[0];
  const float* cstate = (const float*)d_in[1];
  const float* norm_w = (const float*)d_in[2];
  const float* w1     = (const float*)d_in[3];
  const float* b1     = (const float*)d_in[4];
  const float* convw  = (const float*)d_in[5];
  const float* convb  = (const float*)d_in[6];
  const float* xpw    = (const float*)d_in[7];
  const float* xpb    = (const float*)d_in[8];
  const float* dtw    = (const float*)d_in[9];
  const float* dtb    = (const float*)d_in[10];
  const float* alog   = (const float*)d_in[11];
  const float* dparam = (const float*)d_in[12];
  const float* wo     = (const float*)d_in[13];
  const float* bo     = (const float*)d_in[14];
  float* out = (float*)d_out;

  // workspace layout, 39,378,944 B total
  char* wsb = (char*)d_ws;
  u16*   w1b    = (u16*)(wsb + 0);            //  8,388,608 B  [4096][1024] bf16
  u16*   wob    = (u16*)(wsb + 8388608);      //  4,194,304 B  [1024][2048] bf16
  float* rscale = (float*)(wsb + 12582912);   //      8,192 B  [2048]
  float* proj   = (float*)(wsb + 12591104);   //    786,432 B  [2048][96] token-major
  float* projT  = (float*)(wsb + 13377536);   //    786,432 B  [96][2048] transposed
  u16*   xgb    = (u16*)(wsb + 14163968);     // 16,826,368 B  [2][1027][4096] bf16
  u16*   yb     = (u16*)(wsb + 30990336);     //  8,388,608 B  [2][1024][2048] bf16

  k_castw<<<4096, 256, 0, stream>>>(w1, w1b);
  k_castw<<<2048, 256, 0, stream>>>(wo, wob);
  k_rowscale<<<BL, 256, 0, stream>>>(inp, rscale);
  k_gemm1_mfma<<<dim3(64, 32), 256, 0, stream>>>(inp, w1b, b1, rscale, norm_w, xgb);
  k_xprojc<<<BL, 256, 0, stream>>>(xgb, convw, convb, xpw, xpb, proj);
  k_transpose<<<32, 256, 0, stream>>>(proj, projT);
  k_scan<<<2 * DDIM, 256, 0, stream>>>(projT, xgb, convw, convb, dtw, dtb,
                                       alog, dparam, cstate, yb);
  k_gemm2_mfma<<<dim3(16, 32), 256, 0, stream>>>(yb, wob, bo, inp, out);
}